// Round 8
// baseline (514.549 us; speedup 1.0000x reference)
//
#include <hip/hip_runtime.h>

// Problem constants (fixed by the reference)
#define T_SEQ   4096
#define BATCH   32
#define DIM     512
#define MROWS   (T_SEQ * BATCH)          // 131072 GEMM rows
#define S_STRIDE (BATCH * DIM)           // 16384 elements per time step
#define OUT_ELEMS ((size_t)T_SEQ * BATCH * DIM)   // 67108864
#define NCH     32                        // T-chunks for parallel scan
#define CLEN    (T_SEQ / NCH)             // 128 steps per chunk
#define NCHAIN  (BATCH * DIM)             // 16384 independent chains
#define GNWG    1024                      // 256 M-groups x 4 N-tiles

typedef __bf16 bf8_t __attribute__((ext_vector_type(8)));
typedef float  f4_t  __attribute__((ext_vector_type(4)));
typedef unsigned short u16x8 __attribute__((ext_vector_type(8)));
typedef __attribute__((address_space(1))) void gvoid_t;
typedef __attribute__((address_space(3))) void lvoid_t;

__device__ __forceinline__ unsigned short f2bf(float f) {
    unsigned int u = __float_as_uint(f);
    u += 0x7FFFu + ((u >> 16) & 1u);     // round-to-nearest-even
    return (unsigned short)(u >> 16);
}
__device__ __forceinline__ float bf2f(unsigned short b) {
    return __uint_as_float(((unsigned int)b) << 16);
}

// ---------------- f32 -> bf16 convert (weights only) -----------------
__global__ __launch_bounds__(256) void k_cvt(const float* __restrict__ in,
                                             unsigned short* __restrict__ out) {
    size_t i = ((size_t)blockIdx.x * 256 + threadIdx.x) * 8;
    float4 a = *reinterpret_cast<const float4*>(in + i);
    float4 b = *reinterpret_cast<const float4*>(in + i + 4);
    u16x8 o;
    o[0] = f2bf(a.x); o[1] = f2bf(a.y); o[2] = f2bf(a.z); o[3] = f2bf(a.w);
    o[4] = f2bf(b.x); o[5] = f2bf(b.y); o[6] = f2bf(b.z); o[7] = f2bf(b.w);
    *reinterpret_cast<u16x8*>(out + i) = o;
}

// ---------------- m97-style bf16 GEMM  C = A * B^T -------------------
// 128x128 tile, BK=64, 4 waves, 32 KB static LDS (single-buffered,
// 2 barriers/K-step, NO explicit waits — co-resident blocks cover stalls).
// Each block computes 4 M-tiles sequentially (32-step pipeline); C written
// at tile boundaries (stores drain under other blocks' compute).
// XOR swizzle: 16B slot sl of row r stored at sl^(r&7); gll sources
// pre-inverse-swizzled; reads apply the same XOR (conflict-free at BK=64).
// AF32=1: A is f32 -> regs -> cvt -> swizzled ds_write (bit-identical f2bf).
template <int AF32>
__global__ __launch_bounds__(256)
void k_gemm_m97(const void* __restrict__ Ap,
                const unsigned short* __restrict__ B,
                unsigned short* __restrict__ C) {
    __shared__ unsigned short As[128 * 64];
    __shared__ unsigned short Bs[128 * 64];

    const int tid  = threadIdx.x;
    const int lane = tid & 63;
    const int wv   = tid >> 6;          // wave 0..3
    const int wr   = wv >> 1;           // wave M-half
    const int wc   = wv & 1;            // wave N-half
    const int l15  = lane & 15;
    const int l16  = lane >> 4;

    // bijective XCD swizzle; 4 N-tiles of an M-group adjacent -> same XCD L2
    const int s  = (blockIdx.x & 7) * (GNWG / 8) + (blockIdx.x >> 3);
    const int gn = (s & 3) * 128;                 // N-tile
    const size_t gmg = (size_t)(s >> 2) * 512;    // M-group base (4 tiles)

    const unsigned short* Ab = (const unsigned short*)Ap;
    const float*          Af = (const float*)Ap;

    // ---- bf16 tile stage: 4 gll rounds of 32 rows, pre-swizzled source ----
    auto stage16 = [&](const unsigned short* gb, size_t grow0,
                       unsigned short* lbuf, int kt) {
#pragma unroll
        for (int j = 0; j < 4; ++j) {
            const int r = j * 32 + wv * 8 + (lane >> 3);
            const unsigned short* src =
                gb + (grow0 + r) * 512 + kt * 64 + (((lane & 7) ^ (r & 7)) * 8);
            __builtin_amdgcn_global_load_lds((gvoid_t*)src,
                (lvoid_t*)&lbuf[(j * 32 + wv * 8) * 64], 16, 0, 0);
        }
    };

    // ---- f32 A stage (gemm1): thread -> row tid/2, half-row (t&1)*32 ----
    const int ar = tid >> 1;            // 0..127
    const int ah = (tid & 1) * 4;       // slot base 0 or 4

    const int mtiles = 4;
    for (int mt = 0; mt < mtiles; ++mt) {
        const size_t gm = gmg + mt * 128;
        f4_t acc[4][4] = {};

        for (int kt = 0; kt < 8; ++kt) {
            // ---- stage K-step kt ----
            stage16(B, (size_t)gn, Bs, kt);
            if constexpr (AF32) {
                const float* src = Af + (gm + ar) * 512 + kt * 64 + ah * 8;
                float4 f[8];
#pragma unroll
                for (int q = 0; q < 8; ++q)
                    f[q] = *reinterpret_cast<const float4*>(src + q * 4);
#pragma unroll
                for (int q = 0; q < 4; ++q) {
                    u16x8 o;
                    o[0] = f2bf(f[2*q].x); o[1] = f2bf(f[2*q].y);
                    o[2] = f2bf(f[2*q].z); o[3] = f2bf(f[2*q].w);
                    o[4] = f2bf(f[2*q+1].x); o[5] = f2bf(f[2*q+1].y);
                    o[6] = f2bf(f[2*q+1].z); o[7] = f2bf(f[2*q+1].w);
                    *reinterpret_cast<u16x8*>(
                        &As[ar * 64 + ((ah + q) ^ (ar & 7)) * 8]) = o;
                }
            } else {
                stage16(Ab, gm, As, kt);
            }
            __syncthreads();   // drains vmcnt+lgkmcnt: tile visible

            // ---- compute: 16 ds_read_b128 + 32 MFMA ----
            bf8_t af[4][2], bfz[4][2];
#pragma unroll
            for (int m = 0; m < 4; ++m)
#pragma unroll
                for (int ks = 0; ks < 2; ++ks) {
                    const int r  = wr * 64 + m * 16 + l15;
                    const int sl = (ks * 4 + l16) ^ (l15 & 7);
                    af[m][ks] = *reinterpret_cast<const bf8_t*>(
                        (const char*)As + r * 128 + sl * 16);
                }
#pragma unroll
            for (int n = 0; n < 4; ++n)
#pragma unroll
                for (int ks = 0; ks < 2; ++ks) {
                    const int r  = wc * 64 + n * 16 + l15;
                    const int sl = (ks * 4 + l16) ^ (l15 & 7);
                    bfz[n][ks] = *reinterpret_cast<const bf8_t*>(
                        (const char*)Bs + r * 128 + sl * 16);
                }
#pragma unroll
            for (int m = 0; m < 4; ++m)
#pragma unroll
                for (int n = 0; n < 4; ++n)
#pragma unroll
                    for (int ks = 0; ks < 2; ++ks)
                        acc[m][n] = __builtin_amdgcn_mfma_f32_16x16x32_bf16(
                            af[m][ks], bfz[n][ks], acc[m][n], 0, 0, 0);
            __syncthreads();   // all LDS reads done before next stage
        }

        // ---- C-write for this M-tile (stores drain under other blocks) ----
        const int crow0 = l16 * 4;
#pragma unroll
        for (int m = 0; m < 4; ++m)
#pragma unroll
            for (int n = 0; n < 4; ++n) {
                const size_t row0 = gm + (size_t)(wr * 64 + m * 16 + crow0);
                const int    col  = gn + wc * 64 + n * 16 + l15;
#pragma unroll
                for (int r = 0; r < 4; ++r)
                    C[(row0 + r) * 512 + col] = f2bf(acc[m][n][r]);
            }
    }
}

// ------------- chunk-parallel scan, pass 1: per-chunk (A,B) summaries -------
__global__ __launch_bounds__(256)
void k_scan_p1(const unsigned short* __restrict__ q,
               const float* __restrict__ w_hh,
               const float* __restrict__ b_ih,
               float* __restrict__ Asum,
               float* __restrict__ Bsum) {
    const int g = (blockIdx.x & 63) * 256 + threadIdx.x;
    const int c = blockIdx.x >> 6;
    const float w  = w_hh[g & 511];
    const float bs = b_ih[g & 511];
    const unsigned short* p = q + (size_t)c * CLEN * S_STRIDE + g;

    float A = 0.f, Bv = 0.f;
    float s0[8], s1[8];
#pragma unroll
    for (int j = 0; j < 8; ++j) s0[j] = bf2f(p[(size_t)j * S_STRIDE]);
#pragma unroll
    for (int j = 0; j < 8; ++j) s1[j] = bf2f(p[(size_t)(8 + j) * S_STRIDE]);

    for (int j0 = 0; j0 < CLEN; j0 += 16) {
#pragma unroll
        for (int j = 0; j < 8; ++j) {
            float qv = s0[j] + bs;
            A  = fmaxf(fmaf(w, A, qv), 0.f);
            Bv = fmaf(w, Bv, qv);
        }
        if (j0 + 16 < CLEN) {
#pragma unroll
            for (int j = 0; j < 8; ++j) s0[j] = bf2f(p[(size_t)(j0 + 16 + j) * S_STRIDE]);
        }
#pragma unroll
        for (int j = 0; j < 8; ++j) {
            float qv = s1[j] + bs;
            A  = fmaxf(fmaf(w, A, qv), 0.f);
            Bv = fmaf(w, Bv, qv);
        }
        if (j0 + 24 < CLEN) {
#pragma unroll
            for (int j = 0; j < 8; ++j) s1[j] = bf2f(p[(size_t)(j0 + 24 + j) * S_STRIDE]);
        }
    }
    Asum[(size_t)c * NCHAIN + g] = A;
    Bsum[(size_t)c * NCHAIN + g] = Bv;
}

// ------------- pass 2: per-block stitch + exact replay ----------------------
template <int MODE>
__global__ __launch_bounds__(256)
void k_scan_p2(const unsigned short* __restrict__ q,
               const float* __restrict__ w_hh,
               const float* __restrict__ b_ih,
               const float* __restrict__ Asum,
               const float* __restrict__ Bsum,
               float* __restrict__ of32,
               unsigned short* __restrict__ ob16,
               float* __restrict__ hT) {
    const int g = (blockIdx.x & 63) * 256 + threadIdx.x;
    const int c = blockIdx.x >> 6;
    const float w  = w_hh[g & 511];
    const float bs = b_ih[g & 511];

    float cw = w;
#pragma unroll
    for (int i = 0; i < 7; ++i) cw *= cw;      // w^128
    float h = 0.f;
    for (int cc = 0; cc < c; ++cc)
        h = fmaxf(Asum[(size_t)cc * NCHAIN + g], fmaf(cw, h, Bsum[(size_t)cc * NCHAIN + g]));

    const size_t base = (size_t)c * CLEN * S_STRIDE + g;
    const unsigned short* p = q + base;

    float s0[8], s1[8];
#pragma unroll
    for (int j = 0; j < 8; ++j) s0[j] = bf2f(p[(size_t)j * S_STRIDE]);
#pragma unroll
    for (int j = 0; j < 8; ++j) s1[j] = bf2f(p[(size_t)(8 + j) * S_STRIDE]);

    for (int j0 = 0; j0 < CLEN; j0 += 16) {
#pragma unroll
        for (int j = 0; j < 8; ++j) {
            h = fmaxf(fmaf(w, h, s0[j] + bs), 0.f);
            const size_t idx = base + (size_t)(j0 + j) * S_STRIDE;
            if (MODE == 0) of32[idx] = h; else ob16[idx] = f2bf(h);
        }
        if (j0 + 16 < CLEN) {
#pragma unroll
            for (int j = 0; j < 8; ++j) s0[j] = bf2f(p[(size_t)(j0 + 16 + j) * S_STRIDE]);
        }
#pragma unroll
        for (int j = 0; j < 8; ++j) {
            h = fmaxf(fmaf(w, h, s1[j] + bs), 0.f);
            const size_t idx = base + (size_t)(j0 + 8 + j) * S_STRIDE;
            if (MODE == 0) of32[idx] = h; else ob16[idx] = f2bf(h);
        }
        if (j0 + 24 < CLEN) {
#pragma unroll
            for (int j = 0; j < 8; ++j) s1[j] = bf2f(p[(size_t)(j0 + 24 + j) * S_STRIDE]);
        }
    }
    if (c == NCH - 1) hT[g] = h;
}

extern "C" void kernel_launch(void* const* d_in, const int* in_sizes, int n_in,
                              void* d_out, int out_size, void* d_ws, size_t ws_size,
                              hipStream_t stream) {
    const float* x    = (const float*)d_in[0];   // (4096,32,512)
    const float* W_ih = (const float*)d_in[1];   // (2,512,512)
    const float* w_hh = (const float*)d_in[2];   // (2,512)
    const float* b_ih = (const float*)d_in[3];   // (2,512)

    // ---- workspace layout (~139 MB) ----
    unsigned short* proj2 = (unsigned short*)d_ws;                // 134 MB
    unsigned short* Wb    = proj2 + OUT_ELEMS;                    // 1 MB
    float* Asum = (float*)(Wb + 2 * 512 * 512);                   // 2 MB
    float* Bsum = Asum + (size_t)NCH * NCHAIN;                    // 2 MB

    // ---- d_out staging: proj1 (bf16) lower half, ys1 (bf16) upper half ----
    unsigned short* proj1 = (unsigned short*)d_out;
    unsigned short* ys1   = proj1 + OUT_ELEMS;
    float* out = (float*)d_out;
    float* hT  = out + OUT_ELEMS;                                 // h_n (2,32,512)

    const int sgrid = 64 * NCH;             // 2048 blocks for scan passes

    // 1. W -> bf16
    k_cvt<<<524288 / 8 / 256, 256, 0, stream>>>(W_ih, Wb);
    // 2. layer-0 GEMM (A = x f32, fused cvt) -> proj1
    k_gemm_m97<1><<<GNWG, 256, 0, stream>>>(x, Wb, proj1);
    // 3-4. layer-0 chunked scan -> ys1 (bf16) + hT0
    k_scan_p1<<<sgrid, 256, 0, stream>>>(proj1, w_hh, b_ih, Asum, Bsum);
    k_scan_p2<1><<<sgrid, 256, 0, stream>>>(proj1, w_hh, b_ih, Asum, Bsum,
                                            nullptr, ys1, hT);
    // 5. layer-1 GEMM (A = ys1 bf16) -> proj2 (ws)
    k_gemm_m97<0><<<GNWG, 256, 0, stream>>>(ys1, Wb + 512 * 512, proj2);
    // 6-7. layer-1 chunked scan -> final out (f32, overwrites proj1/ys1) + hT1
    k_scan_p1<<<sgrid, 256, 0, stream>>>(proj2, w_hh + DIM, b_ih + DIM, Asum, Bsum);
    k_scan_p2<0><<<sgrid, 256, 0, stream>>>(proj2, w_hh + DIM, b_ih + DIM, Asum, Bsum,
                                            out, nullptr, hT + NCHAIN);
}

// Round 10
// 460.432 us; speedup vs baseline: 1.1175x; 1.1175x over previous
//
#include <hip/hip_runtime.h>

// Problem constants (fixed by the reference)
#define T_SEQ   4096
#define BATCH   32
#define DIM     512
#define MROWS   (T_SEQ * BATCH)          // 131072 GEMM rows
#define S_STRIDE (BATCH * DIM)           // 16384 elements per time step
#define OUT_ELEMS ((size_t)T_SEQ * BATCH * DIM)   // 67108864
#define NCH     32                        // T-chunks for parallel scan
#define CLEN    (T_SEQ / NCH)             // 128 steps per chunk
#define NCHAIN  (BATCH * DIM)             // 16384 independent chains
#define GNWG    4096                      // 1024 M-tiles x 4 N-tiles

typedef __bf16 bf8_t __attribute__((ext_vector_type(8)));
typedef float  f4_t  __attribute__((ext_vector_type(4)));
typedef unsigned short u16x8 __attribute__((ext_vector_type(8)));
typedef __attribute__((address_space(1))) void gvoid_t;
typedef __attribute__((address_space(3))) void lvoid_t;

__device__ __forceinline__ unsigned short f2bf(float f) {
    unsigned int u = __float_as_uint(f);
    u += 0x7FFFu + ((u >> 16) & 1u);     // round-to-nearest-even
    return (unsigned short)(u >> 16);
}
__device__ __forceinline__ float bf2f(unsigned short b) {
    return __uint_as_float(((unsigned int)b) << 16);
}

#define VMC0 asm volatile("s_waitcnt vmcnt(0)" ::: "memory")
#define VMC4 asm volatile("s_waitcnt vmcnt(4)" ::: "memory")
#define VMC6 asm volatile("s_waitcnt vmcnt(6)" ::: "memory")
#define VMC8 asm volatile("s_waitcnt vmcnt(8)" ::: "memory")
#define LGKM0 asm volatile("s_waitcnt lgkmcnt(0)" ::: "memory")

// ---------------- f32 -> bf16 convert (weights only) -----------------
__global__ __launch_bounds__(256) void k_cvt(const float* __restrict__ in,
                                             unsigned short* __restrict__ out) {
    size_t i = ((size_t)blockIdx.x * 256 + threadIdx.x) * 8;
    float4 a = *reinterpret_cast<const float4*>(in + i);
    float4 b = *reinterpret_cast<const float4*>(in + i + 4);
    u16x8 o;
    o[0] = f2bf(a.x); o[1] = f2bf(a.y); o[2] = f2bf(a.z); o[3] = f2bf(a.w);
    o[4] = f2bf(b.x); o[5] = f2bf(b.y); o[6] = f2bf(b.z); o[7] = f2bf(b.w);
    *reinterpret_cast<u16x8*>(out + i) = o;
}

// ---------------- triple-buffered bf16 GEMM  C = A * B^T -------------
// 128x128 tile, BK=32, 4 waves, 3 LDS buffers (48 KB -> 3 blocks/CU).
// Per K-step: issue stage(s+2); compute s; vmcnt(4/6) [= step s+1 landed,
// NEVER 0 mid-loop]; one raw s_barrier. Stage target = region read at s-1,
// barrier-separated: hazard-free. Swizzle: 16B slot sl of row r stored at
// sl ^ (r&3) ^ ((r>>2)&3)  -> max 2-way bank conflict (free). gll sources
// pre-inverse-swizzled. AF32=1: A f32 -> ping-pong reg arrays (P even /
// Q odd tiles, all indices literal) -> cvt -> swizzled ds_write at step end.
template <int AF32>
__global__ __launch_bounds__(256, 3)
void k_gemm_tb(const void* __restrict__ Ap,
               const unsigned short* __restrict__ Bp,
               unsigned short* __restrict__ C) {
    __shared__ unsigned short As[3][4096];   // 3 x 128x32
    __shared__ unsigned short Bs[3][4096];

    const int tid  = threadIdx.x;
    const int lane = tid & 63;
    const int wv   = tid >> 6;
    const int wr   = wv >> 1;
    const int wc   = wv & 1;
    const int l15  = lane & 15;
    const int l16q = lane >> 4;                       // true k-slot 0..3
    const int swl  = (l15 & 3) ^ ((l15 >> 2) & 3);    // read swizzle

    // staging constants: thread owns slots li0=tid, li1=256+tid
    const int r0 = tid >> 2,         sl0 = tid & 3;
    const int r1 = (256 + tid) >> 2;                  // (256+tid)&3 == tid&3
    const int ko0 = (sl0 ^ ((r0 & 3) ^ ((r0 >> 2) & 3))) * 8;
    const int ko1 = (sl0 ^ ((r1 & 3) ^ ((r1 >> 2) & 3))) * 8;

    // bijective XCD swizzle; 4 N-tiles of an M-tile adjacent -> same XCD L2
    const int s_  = (blockIdx.x & 7) * (GNWG / 8) + (blockIdx.x >> 3);
    const int gn  = (s_ & 3) * 128;
    const size_t gm = (size_t)(s_ >> 2) * 128;

    const unsigned short* Ab = (const unsigned short*)Ap;
    const float*          Af = (const float*)Ap;

    auto stageTo = [&](unsigned short* buf, const unsigned short* gb,
                       size_t grow0, int kt) {
        __builtin_amdgcn_global_load_lds(
            (gvoid_t*)(gb + (grow0 + r0) * 512 + kt * 32 + ko0),
            (lvoid_t*)&buf[(wv * 64) * 8], 16, 0, 0);
        __builtin_amdgcn_global_load_lds(
            (gvoid_t*)(gb + (grow0 + r1) * 512 + kt * 32 + ko1),
            (lvoid_t*)&buf[(256 + wv * 64) * 8], 16, 0, 0);
    };

#define LOADAF(S, kt) do {                                                   \
        const float* pa_ = Af + (gm + r0) * 512 + (kt) * 32 + ko0;           \
        const float* pb_ = Af + (gm + r1) * 512 + (kt) * 32 + ko1;           \
        S[0] = *reinterpret_cast<const float4*>(pa_);                        \
        S[1] = *reinterpret_cast<const float4*>(pa_ + 4);                    \
        S[2] = *reinterpret_cast<const float4*>(pb_);                        \
        S[3] = *reinterpret_cast<const float4*>(pb_ + 4);                    \
    } while (0)

#define WRITEAF(S, buf) do {                                                 \
        u16x8 oa_, ob_;                                                      \
        oa_[0]=f2bf(S[0].x); oa_[1]=f2bf(S[0].y); oa_[2]=f2bf(S[0].z); oa_[3]=f2bf(S[0].w); \
        oa_[4]=f2bf(S[1].x); oa_[5]=f2bf(S[1].y); oa_[6]=f2bf(S[1].z); oa_[7]=f2bf(S[1].w); \
        ob_[0]=f2bf(S[2].x); ob_[1]=f2bf(S[2].y); ob_[2]=f2bf(S[2].z); ob_[3]=f2bf(S[2].w); \
        ob_[4]=f2bf(S[3].x); ob_[5]=f2bf(S[3].y); ob_[6]=f2bf(S[3].z); ob_[7]=f2bf(S[3].w); \
        *reinterpret_cast<u16x8*>(&(buf)[tid * 8])         = oa_;            \
        *reinterpret_cast<u16x8*>(&(buf)[(256 + tid) * 8]) = ob_;            \
    } while (0)

#define COMPUTE(bA, bB) do {                                                 \
        bf8_t af_[4], bf_[4];                                                \
        _Pragma("unroll")                                                    \
        for (int m = 0; m < 4; ++m)                                          \
            af_[m] = *reinterpret_cast<const bf8_t*>(                        \
                &(bA)[(wr * 64 + m * 16 + l15) * 32 + (l16q ^ swl) * 8]);    \
        _Pragma("unroll")                                                    \
        for (int n = 0; n < 4; ++n)                                          \
            bf_[n] = *reinterpret_cast<const bf8_t*>(                        \
                &(bB)[(wc * 64 + n * 16 + l15) * 32 + (l16q ^ swl) * 8]);    \
        _Pragma("unroll")                                                    \
        for (int m = 0; m < 4; ++m)                                          \
            _Pragma("unroll")                                                \
            for (int n = 0; n < 4; ++n)                                      \
                acc[m][n] = __builtin_amdgcn_mfma_f32_16x16x32_bf16(         \
                    af_[m], bf_[n], acc[m][n], 0, 0, 0);                     \
    } while (0)

    f4_t acc[4][4] = {};
    float4 P[4], Q[4];     // AF32 ping-pong (even/odd tiles), literal indices

    unsigned short *cA = As[0], *cB = Bs[0];   // current (tile s)
    unsigned short *nA = As[1], *nB = Bs[1];   // next    (tile s+1)
    unsigned short *fA = As[2], *fB = Bs[2];   // far     (tile s+2 stage tgt)

    // ---- prologue: tiles 0,1 ----
    if constexpr (AF32) {
        LOADAF(P, 0); stageTo(cB, Bp, (size_t)gn, 0);
        LOADAF(Q, 1); stageTo(nB, Bp, (size_t)gn, 1);
        VMC8;                       // P (tile0 A) landed
        WRITEAF(P, cA);
        VMC6;                       // B(0) landed
        LGKM0;
    } else {
        stageTo(cA, Ab, gm, 0); stageTo(cB, Bp, (size_t)gn, 0);
        stageTo(nA, Ab, gm, 1); stageTo(nB, Bp, (size_t)gn, 1);
        VMC4;                       // tile0 landed
    }
    __builtin_amdgcn_s_barrier();

    // ---- main loop: 16 K-steps, parity-static reg sets ----
#define GSTEP(s, SI, SW_) do {                                               \
        if ((s) + 2 < 16) {                                                  \
            stageTo(fB, Bp, (size_t)gn, (s) + 2);                            \
            if constexpr (AF32) { LOADAF(SI, (s) + 2); }                     \
            else stageTo(fA, Ab, gm, (s) + 2);                               \
        }                                                                    \
        COMPUTE(cA, cB);                                                     \
        if ((s) + 2 < 16) { if constexpr (AF32) { VMC6; } else { VMC4; } }   \
        else if ((s) == 14) { VMC0; }                                        \
        if constexpr (AF32) {                                                \
            if ((s) + 1 < 16) { WRITEAF(SW_, nA); LGKM0; }                   \
        }                                                                    \
        if ((s) < 15) __builtin_amdgcn_s_barrier();                          \
    } while (0)

    for (int s = 0; s < 16; s += 2) {
        GSTEP(s, P, Q);        // even: issue tile s+2 -> P, write tile s+1 (Q)
        { unsigned short* t;   // rotate for odd step: cur<-next<-far<-cur
          t = cA; cA = nA; nA = fA; fA = t;
          t = cB; cB = nB; nB = fB; fB = t; }
        GSTEP(s + 1, Q, P);
        { unsigned short* t;
          t = cA; cA = nA; nA = fA; fA = t;
          t = cB; cB = nB; nB = fB; fB = t; }
    }
#undef GSTEP
#undef COMPUTE
#undef WRITEAF
#undef LOADAF

    // ---- C-write: C/D layout col=lane&15, row=(lane>>4)*4+reg ----
    const int crow0 = l16q * 4;
#pragma unroll
    for (int m = 0; m < 4; ++m)
#pragma unroll
        for (int n = 0; n < 4; ++n) {
            const size_t row0 = gm + (size_t)(wr * 64 + m * 16 + crow0);
            const int    col  = gn + wc * 64 + n * 16 + l15;
#pragma unroll
            for (int r = 0; r < 4; ++r)
                C[(row0 + r) * 512 + col] = f2bf(acc[m][n][r]);
        }
}

// ------------- chunk-parallel scan, pass 1: per-chunk (A,B) summaries -------
__global__ __launch_bounds__(256)
void k_scan_p1(const unsigned short* __restrict__ q,
               const float* __restrict__ w_hh,
               const float* __restrict__ b_ih,
               float* __restrict__ Asum,
               float* __restrict__ Bsum) {
    const int g = (blockIdx.x & 63) * 256 + threadIdx.x;
    const int c = blockIdx.x >> 6;
    const float w  = w_hh[g & 511];
    const float bs = b_ih[g & 511];
    const unsigned short* p = q + (size_t)c * CLEN * S_STRIDE + g;

    float A = 0.f, Bv = 0.f;
    float s0[8], s1[8];
#pragma unroll
    for (int j = 0; j < 8; ++j) s0[j] = bf2f(p[(size_t)j * S_STRIDE]);
#pragma unroll
    for (int j = 0; j < 8; ++j) s1[j] = bf2f(p[(size_t)(8 + j) * S_STRIDE]);

    for (int j0 = 0; j0 < CLEN; j0 += 16) {
#pragma unroll
        for (int j = 0; j < 8; ++j) {
            float qv = s0[j] + bs;
            A  = fmaxf(fmaf(w, A, qv), 0.f);
            Bv = fmaf(w, Bv, qv);
        }
        if (j0 + 16 < CLEN) {
#pragma unroll
            for (int j = 0; j < 8; ++j) s0[j] = bf2f(p[(size_t)(j0 + 16 + j) * S_STRIDE]);
        }
#pragma unroll
        for (int j = 0; j < 8; ++j) {
            float qv = s1[j] + bs;
            A  = fmaxf(fmaf(w, A, qv), 0.f);
            Bv = fmaf(w, Bv, qv);
        }
        if (j0 + 24 < CLEN) {
#pragma unroll
            for (int j = 0; j < 8; ++j) s1[j] = bf2f(p[(size_t)(j0 + 24 + j) * S_STRIDE]);
        }
    }
    Asum[(size_t)c * NCHAIN + g] = A;
    Bsum[(size_t)c * NCHAIN + g] = Bv;
}

// ------------- pass 2: per-block stitch + exact replay ----------------------
template <int MODE>
__global__ __launch_bounds__(256)
void k_scan_p2(const unsigned short* __restrict__ q,
               const float* __restrict__ w_hh,
               const float* __restrict__ b_ih,
               const float* __restrict__ Asum,
               const float* __restrict__ Bsum,
               float* __restrict__ of32,
               unsigned short* __restrict__ ob16,
               float* __restrict__ hT) {
    const int g = (blockIdx.x & 63) * 256 + threadIdx.x;
    const int c = blockIdx.x >> 6;
    const float w  = w_hh[g & 511];
    const float bs = b_ih[g & 511];

    float cw = w;
#pragma unroll
    for (int i = 0; i < 7; ++i) cw *= cw;      // w^128
    float h = 0.f;
    for (int cc = 0; cc < c; ++cc)
        h = fmaxf(Asum[(size_t)cc * NCHAIN + g], fmaf(cw, h, Bsum[(size_t)cc * NCHAIN + g]));

    const size_t base = (size_t)c * CLEN * S_STRIDE + g;
    const unsigned short* p = q + base;

    float s0[8], s1[8];
#pragma unroll
    for (int j = 0; j < 8; ++j) s0[j] = bf2f(p[(size_t)j * S_STRIDE]);
#pragma unroll
    for (int j = 0; j < 8; ++j) s1[j] = bf2f(p[(size_t)(8 + j) * S_STRIDE]);

    for (int j0 = 0; j0 < CLEN; j0 += 16) {
#pragma unroll
        for (int j = 0; j < 8; ++j) {
            h = fmaxf(fmaf(w, h, s0[j] + bs), 0.f);
            const size_t idx = base + (size_t)(j0 + j) * S_STRIDE;
            if (MODE == 0) of32[idx] = h; else ob16[idx] = f2bf(h);
        }
        if (j0 + 16 < CLEN) {
#pragma unroll
            for (int j = 0; j < 8; ++j) s0[j] = bf2f(p[(size_t)(j0 + 16 + j) * S_STRIDE]);
        }
#pragma unroll
        for (int j = 0; j < 8; ++j) {
            h = fmaxf(fmaf(w, h, s1[j] + bs), 0.f);
            const size_t idx = base + (size_t)(j0 + 8 + j) * S_STRIDE;
            if (MODE == 0) of32[idx] = h; else ob16[idx] = f2bf(h);
        }
        if (j0 + 24 < CLEN) {
#pragma unroll
            for (int j = 0; j < 8; ++j) s1[j] = bf2f(p[(size_t)(j0 + 24 + j) * S_STRIDE]);
        }
    }
    if (c == NCH - 1) hT[g] = h;
}

extern "C" void kernel_launch(void* const* d_in, const int* in_sizes, int n_in,
                              void* d_out, int out_size, void* d_ws, size_t ws_size,
                              hipStream_t stream) {
    const float* x    = (const float*)d_in[0];   // (4096,32,512)
    const float* W_ih = (const float*)d_in[1];   // (2,512,512)
    const float* w_hh = (const float*)d_in[2];   // (2,512)
    const float* b_ih = (const float*)d_in[3];   // (2,512)

    // ---- workspace layout (~139 MB) ----
    unsigned short* proj2 = (unsigned short*)d_ws;                // 134 MB
    unsigned short* Wb    = proj2 + OUT_ELEMS;                    // 1 MB
    float* Asum = (float*)(Wb + 2 * 512 * 512);                   // 2 MB
    float* Bsum = Asum + (size_t)NCH * NCHAIN;                    // 2 MB

    // ---- d_out staging: proj1 (bf16) lower half, ys1 (bf16) upper half ----
    unsigned short* proj1 = (unsigned short*)d_out;
    unsigned short* ys1   = proj1 + OUT_ELEMS;
    float* out = (float*)d_out;
    float* hT  = out + OUT_ELEMS;                                 // h_n (2,32,512)

    const int sgrid = 64 * NCH;             // 2048 blocks for scan passes

    // 1. W -> bf16
    k_cvt<<<524288 / 8 / 256, 256, 0, stream>>>(W_ih, Wb);
    // 2. layer-0 GEMM (A = x f32, fused cvt) -> proj1
    k_gemm_tb<1><<<GNWG, 256, 0, stream>>>(x, Wb, proj1);
    // 3-4. layer-0 chunked scan -> ys1 (bf16) + hT0
    k_scan_p1<<<sgrid, 256, 0, stream>>>(proj1, w_hh, b_ih, Asum, Bsum);
    k_scan_p2<1><<<sgrid, 256, 0, stream>>>(proj1, w_hh, b_ih, Asum, Bsum,
                                            nullptr, ys1, hT);
    // 5. layer-1 GEMM (A = ys1 bf16) -> proj2 (ws)
    k_gemm_tb<0><<<GNWG, 256, 0, stream>>>(ys1, Wb + 512 * 512, proj2);
    // 6-7. layer-1 chunked scan -> final out (f32, overwrites proj1/ys1) + hT1
    k_scan_p1<<<sgrid, 256, 0, stream>>>(proj2, w_hh + DIM, b_ih + DIM, Asum, Bsum);
    k_scan_p2<0><<<sgrid, 256, 0, stream>>>(proj2, w_hh + DIM, b_ih + DIM, Asum, Bsum,
                                            out, nullptr, hT + NCHAIN);
}